// Round 13
// baseline (105.625 us; speedup 1.0000x reference)
//
#include <hip/hip_runtime.h>
#include <math.h>

#define NPG 128      // nodes per graph
#define HID 64
#define ICH 151
#define EPG 2048     // edges per graph
#define TPB 512      // 8 waves
#define EPT (EPG / TPB)
#define KP  160      // W1T padded K (5 MFMA k-steps of 32)
#define XSS 168      // xs row stride, bf16 (336B: 16B-aligned, 2-way banks)
#define HTS 136      // h^T row stride, bf16 (272B: 16B-aligned)
#define ASS 132      // As row stride, f32 (528B: 16B-aligned)
#define XS_OFF 17408 // byte offset of xs/As region (= ht bytes)
#define SMEM_BYTES (XS_OFF + NPG * XSS * 2)   // 17408 + 43008 = 60416

typedef __attribute__((ext_vector_type(8))) short  short8;   // bf16x8 frag
typedef __attribute__((ext_vector_type(4))) float  floatx4;  // f32x4 acc

// software fp32->bf16 RNE (proven R4/R6/R8/R10-R12; cvt_pk asm NaN'd R7/R9)
static __device__ __forceinline__ unsigned short f2bf(float v) {
    unsigned u = __builtin_bit_cast(unsigned, v);
    return (unsigned short)((u + 0x7fffu + ((u >> 16) & 1u)) >> 16);
}
static __device__ __forceinline__ unsigned packbf(float a, float b) {
    return (unsigned)f2bf(a) | ((unsigned)f2bf(b) << 16);
}
static __device__ __forceinline__ short8 pack8(const float* v) {
    union { unsigned u[4]; short8 s; } r;
    r.u[0] = packbf(v[0], v[1]);
    r.u[1] = packbf(v[2], v[3]);
    r.u[2] = packbf(v[4], v[5]);
    r.u[3] = packbf(v[6], v[7]);
    return r.s;
}

// ---- prep: W1 [151][64] f32 -> W1T [64][160] bf16 (k-pad zeroed) ----
__global__ __launch_bounds__(512) void gcn_prep(const float* __restrict__ W1,
                                                short* __restrict__ W1T) {
    int i = threadIdx.x + blockIdx.x * 512;          // 10240 elements exactly
    if (i < HID * KP) {
        int ch = i / KP, k = i - ch * KP;
        W1T[i] = (short)f2bf((k < ICH) ? W1[k * HID + ch] : 0.0f);
    }
}

__global__ __launch_bounds__(TPB, 6) void gcn_fused(
    const float* __restrict__ x,       // [N,151]
    const int*   __restrict__ erow,    // [E]
    const int*   __restrict__ ecol,    // [E]
    const float* __restrict__ ew,      // [E]
    const short* __restrict__ W1T,     // [64][160] bf16 (prepped)
    const float* __restrict__ b1,      // [64]
    const float* __restrict__ Wlin,    // [8192]
    const float* __restrict__ blin,    // [1]
    float* __restrict__ out)           // [B]
{
    // Phase-aliased LDS (60416 B + ~1KB statics -> 2 blocks/CU):
    //   ht = smem[0 .. 17408)        64x136 bf16 h^T (GEMM out, agg B-frags)
    //   xs = smem[17408 .. 60416)    128x168 bf16 x tile (GEMM staging)
    //   As = smem[17408 .. 51200)    64x132 f32 half-adjacency (agg, xs dead)
    __shared__ __align__(16) char smem[SMEM_BYTES];
    __shared__ float deg[NPG];
    __shared__ float dinv[NPG];
    __shared__ float red[TPB / 64];

    short* ht = (short*)smem;
    short* xs = (short*)(smem + XS_OFF);
    float* As = (float*)(smem + XS_OFF);

    const int t    = threadIdx.x;
    const int g    = blockIdx.x;
    const int lane = t & 63;
    const int wv   = t >> 6;
    const int c16  = lane & 15;
    const int kq   = (lane >> 4) * 8;

    if (t < NPG) deg[t] = 1.0f;                       // self-loop weight

    // ---- edges: one coalesced scan, packed into regs ----
    int   ep_[EPT];                                   // (cl<<7) | rl
    float nw_[EPT];
    const int ebase = g * EPG;
    #pragma unroll
    for (int it = 0; it < EPT; ++it) {
        int e = ebase + t + it * TPB;
        int rl = erow[e] & (NPG - 1);
        int cl = ecol[e] & (NPG - 1);
        ep_[it] = (cl << 7) | rl;
        nw_[it] = ew[e];
    }

    // ---- stage x: coalesced dword-pair reads -> packed dword LDS writes ----
    {
        const float* xg = x + (size_t)g * (NPG * ICH);
        #pragma unroll
        for (int itr = 0; itr < 19; ++itr) {          // 19*512 = 9728 = 128*76
            int p = itr * TPB + t;
            unsigned row = (unsigned)p / 76u;         // magic-mul
            unsigned kd  = (unsigned)p - 76u * row;
            int k = 2 * (int)kd;                      // k <= 150
            float a = xg[row * ICH + k];
            float b = (k + 1 < ICH) ? xg[row * ICH + k + 1] : 0.0f;
            *(unsigned*)&xs[row * XSS + k] = packbf(a, b);
        }
        // zero pad k = 152..158 (s=4,kq=24 frag reads touch k<160)
        int zr = t >> 2, zk = 152 + ((t & 3) << 1);
        *(unsigned*)&xs[zr * XSS + zk] = 0u;
    }
    __syncthreads();                                   // bar1: xs + deg-init ready

    // ---- x A-fragments from LDS (b128, issued BEFORE any other ds op) ----
    short8 af[5];
    #pragma unroll
    for (int s = 0; s < 5; ++s)
        af[s] = *(const short8*)&xs[(wv * 16 + c16) * XSS + s * 32 + kq];

    // ---- GEMM h = x @ W1 -> ht; B-frags = 16B vector loads from W1T ----
    #pragma unroll
    for (int n = 0; n < 4; ++n) {
        floatx4 acc = {0.0f, 0.0f, 0.0f, 0.0f};
        #pragma unroll
        for (int s = 0; s < 5; ++s) {
            short8 b = *(const short8*)&W1T[(n * 16 + c16) * KP + s * 32 + kq];
            acc = __builtin_amdgcn_mfma_f32_16x16x32_bf16(af[s], b, acc, 0, 0, 0);
        }
        // D: row = (lane>>4)*4 + r, col = n*16 + c16  -> ht[col][row]
        int col = n * 16 + c16;
        int row = wv * 16 + (lane >> 4) * 4;
        *(int2*)&ht[col * HTS + row] =
            make_int2((int)packbf(acc[0], acc[1]), (int)packbf(acc[2], acc[3]));
    }

    // ---- degree atomics (after GEMM: keeps MFMA off the atomic lgkm queue) ----
    #pragma unroll
    for (int it = 0; it < EPT; ++it)
        atomicAdd(&deg[ep_[it] >> 7], nw_[it]);
    __syncthreads();                                   // bar2: deg + ht done, xs dead

    if (t < NPG) dinv[t] = rsqrtf(deg[t]);             // deg >= 1 always
    __syncthreads();                                   // bar3: dinv ready

    #pragma unroll
    for (int it = 0; it < EPT; ++it) {                 // precompute edge norms once
        int rl = ep_[it] & (NPG - 1), cl = ep_[it] >> 7;
        nw_[it] = dinv[rl] * nw_[it] * dinv[cl];
    }

    // ---- aggregation in 2 dst-halves: build As (64x128) then MFMA ----
    float partial = 0.0f;
    const int mrow = (wv >> 1) * 16 + c16;             // dst row within half

    for (int half = 0; half < 2; ++half) {
        for (int p = t; p < 64 * ASS / 4; p += TPB)    // zero half-A
            ((floatx4*)As)[p] = (floatx4){0.0f, 0.0f, 0.0f, 0.0f};
        __syncthreads();                               // barA: zero done

        #pragma unroll
        for (int it = 0; it < EPT; ++it) {
            int cl = ep_[it] >> 7;
            if ((cl >> 6) == half)
                atomicAdd(&As[(cl & 63) * ASS + (ep_[it] & (NPG - 1))], nw_[it]);
        }
        if (t < 64) {                                  // diagonal self-loop
            int i = half * 64 + t;
            atomicAdd(&As[t * ASS + i], dinv[i] * dinv[i]);
        }
        __syncthreads();                               // barB: As built

        short8 afr[4];                                 // A frags -> bf16
        #pragma unroll
        for (int ks = 0; ks < 4; ++ks) {
            const float* ap = &As[mrow * ASS + ks * 32 + kq];
            floatx4 a0 = *(const floatx4*)ap;
            floatx4 a1 = *(const floatx4*)(ap + 4);
            float v[8] = {a0[0], a0[1], a0[2], a0[3], a1[0], a1[1], a1[2], a1[3]};
            afr[ks] = pack8(v);
        }
        #pragma unroll
        for (int nn = 0; nn < 2; ++nn) {
            int nt2 = (wv & 1) * 2 + nn;
            floatx4 acc = {0.0f, 0.0f, 0.0f, 0.0f};
            #pragma unroll
            for (int ks = 0; ks < 4; ++ks) {
                short8 b = *(const short8*)&ht[(nt2 * 16 + c16) * HTS + ks * 32 + kq];
                acc = __builtin_amdgcn_mfma_f32_16x16x32_bf16(afr[ks], b, acc, 0, 0, 0);
            }
            int col = nt2 * 16 + c16;
            float b1v = b1[col];
            int node0 = half * 64 + (wv >> 1) * 16 + (lane >> 4) * 4;
            #pragma unroll
            for (int r = 0; r < 4; ++r) {
                float v = fmaxf(acc[r] + b1v, 0.0f);
                partial += v * Wlin[(node0 + r) * HID + col];
            }
        }
        __syncthreads();                               // barC: As reads done
    }

    // ---- block reduction + sigmoid ----
    #pragma unroll
    for (int o = 32; o > 0; o >>= 1)
        partial += __shfl_down(partial, o, 64);
    if (lane == 0) red[wv] = partial;
    __syncthreads();
    if (t == 0) {
        float tot = blin[0];
        #pragma unroll
        for (int i = 0; i < TPB / 64; ++i) tot += red[i];
        out[g] = 1.0f / (1.0f + expf(-tot));
    }
}

extern "C" void kernel_launch(void* const* d_in, const int* in_sizes, int n_in,
                              void* d_out, int out_size, void* d_ws, size_t ws_size,
                              hipStream_t stream) {
    const float* x    = (const float*)d_in[0];
    const int*   ei   = (const int*)d_in[1];
    const float* ew   = (const float*)d_in[2];
    const float* W1   = (const float*)d_in[4];
    const float* b1   = (const float*)d_in[5];
    const float* Wlin = (const float*)d_in[6];
    const float* blin = (const float*)d_in[7];
    float* out = (float*)d_out;

    const int E = in_sizes[1] / 2;     // edge_index is [2, E]
    const int B = out_size;            // 2048 graphs

    short* W1T = (short*)d_ws;         // [64][160] bf16 = 20480 B

    gcn_prep<<<(HID * KP + 511) / 512, 512, 0, stream>>>(W1, W1T);
    gcn_fused<<<B, TPB, 0, stream>>>(x, ei, ei + E, ew, W1T, b1, Wlin, blin, out);
}